// Round 5
// baseline (259.892 us; speedup 1.0000x reference)
//
#include <hip/hip_runtime.h>
#include <stdint.h>

#define Bz 2
#define Sz 2048
#define Dz 1024
#define Hz 16
#define HDz 64
#define Mz (Bz*Sz)   // 4096

typedef unsigned short u16;
typedef __attribute__((ext_vector_type(8))) __bf16 bf16x8;
typedef __attribute__((ext_vector_type(4))) __bf16 bf16x4;
typedef __attribute__((ext_vector_type(8))) unsigned short u16x8;
typedef __attribute__((ext_vector_type(4))) float f32x4;
typedef __attribute__((ext_vector_type(4))) short s16x4;

#define C1 0.1803368801111243f   /* 0.125 * log2(e) */

__device__ __forceinline__ u16 f2bf(float f) {
  union { float f; unsigned u; } v; v.f = f;
  unsigned r = v.u + 0x7fffu + ((v.u >> 16) & 1u);
  return (u16)(r >> 16);
}

__device__ __forceinline__ void async16(void* lds, const void* g) {
  __builtin_amdgcn_global_load_lds(
      (const __attribute__((address_space(1))) unsigned int*)g,
      (__attribute__((address_space(3))) unsigned int*)lds, 16, 0, 0);
}

// ------------- fp32 -> bf16 for q/k/v in one launch (grid.y selects) -------------
__global__ void cvt3_kernel(const float* __restrict__ q, const float* __restrict__ k,
                            const float* __restrict__ v,
                            u16* __restrict__ xq, u16* __restrict__ xk, u16* __restrict__ xv,
                            int n4) {
  const float* in = blockIdx.y == 0 ? q : blockIdx.y == 1 ? k : v;
  u16* out = blockIdx.y == 0 ? xq : blockIdx.y == 1 ? xk : xv;
  int i = blockIdx.x * blockDim.x + threadIdx.x;
  if (i < n4) {
    float4 t = ((const float4*)in)[i];
    ((ushort4*)out)[i] = make_ushort4(f2bf(t.x), f2bf(t.y), f2bf(t.z), f2bf(t.w));
  }
}

// ------- W[K][N] fp32 -> Wt[N][K] bf16 (transpose+convert), grid.z selects matrix -------
__global__ void wt_cvt_kernel(const float* __restrict__ w0, const float* __restrict__ w1,
                              const float* __restrict__ w2, const float* __restrict__ w3,
                              u16* __restrict__ Wt /* 4 stacked [N][K] */) {
  const float* W = blockIdx.z == 0 ? w0 : blockIdx.z == 1 ? w1 : blockIdx.z == 2 ? w2 : w3;
  u16* o = Wt + (size_t)blockIdx.z * Dz * Dz;
  __shared__ __align__(16) float t[32][33];
  int n0 = blockIdx.x * 32, k0 = blockIdx.y * 32;
  int x = threadIdx.x, y = threadIdx.y;   // block (32,8)
#pragma unroll
  for (int i = 0; i < 4; ++i)
    t[y + i*8][x] = W[(size_t)(k0 + y + i*8) * Dz + n0 + x];
  __syncthreads();
#pragma unroll
  for (int i = 0; i < 4; ++i)
    o[(size_t)(n0 + y + i*8) * Dz + k0 + x] = f2bf(t[x][y + i*8]);
}

// ---- Vp[B*S][D] bf16 -> Vt[B][H][HD][S'] bf16 (per-head transpose + s-perm) ----
// Column order within each 64-s block is PERMUTED for attn's b128 PV reads:
// local s64 = ns*16 + qd*4 + j  (ns,qd in 0..3, j in 0..3)  ->  col' = qd*16 + ns*4 + j.
// So strips (2np, 2np+1) at a given qd are 8 contiguous u16 -> one conflict-free b128.
__global__ void __launch_bounds__(256)
vtrans_kernel(const u16* __restrict__ Vp, u16* __restrict__ Vt) {
  __shared__ __align__(16) u16 t[64][72];
  int s0 = blockIdx.x * 64, bh = blockIdx.y;
  int b = bh >> 4;
  int h = bh & 15;
  int tid = threadIdx.x;
#pragma unroll
  for (int p = 0; p < 4; ++p) {
    int c = p * 256 + tid;
    int row = c >> 4, off = (c & 15) * 4;
    ushort4 v = *(const ushort4*)(Vp + (size_t)(b * Sz + s0 + row) * Dz + h * 64 + off);
    *(ushort4*)&t[row][off] = v;
  }
  __syncthreads();
#pragma unroll
  for (int p = 0; p < 4; ++p) {
    int c = p * 256 + tid;
    int d = c >> 4, Q = c & 15;                    // output quad index (col' = Q*4)
    int src = (Q & 3) * 16 + (Q >> 2) * 4;         // ns=Q&3, qd=Q>>2 -> s-base
    ushort4 v = make_ushort4(t[src + 0][d], t[src + 1][d], t[src + 2][d], t[src + 3][d]);
    *(ushort4*)(Vt + (size_t)(bh * 64 + d) * Sz + s0 + Q * 4) = v;
  }
}

// -------- fused QKV GEMM: 128x128 tile; blockIdx.x>>3 selects {Q,K,V} --------
// Q output is pre-scaled by C1 (= 1/sqrt(HD) * log2(e)) so attn's softmax is pure exp2.
__global__ void __launch_bounds__(256)
gemm_qkv(const u16* __restrict__ xq, const u16* __restrict__ xk, const u16* __restrict__ xv,
         const u16* __restrict__ Wt3,
         const float* __restrict__ bq, const float* __restrict__ bk, const float* __restrict__ bv,
         u16* __restrict__ Qp, u16* __restrict__ Kp, u16* __restrict__ Vp)
{
  __shared__ __align__(16) u16 lA[128][32];
  __shared__ __align__(16) u16 lB[128][32];
  const int sel = blockIdx.x >> 3;
  const int n0 = (blockIdx.x & 7) * 128;
  const int m0 = blockIdx.y * 128;
  const u16* A = sel == 0 ? xq : sel == 1 ? xk : xv;
  const u16* Bt = Wt3 + (size_t)sel * Dz * Dz;
  const float* bias = sel == 0 ? bq : sel == 1 ? bk : bv;
  u16* Cv = sel == 0 ? Qp : sel == 1 ? Kp : Vp;
  const float cs = sel == 0 ? C1 : 1.0f;

  const int tid = threadIdx.x;
  const int w = tid >> 6, lane = tid & 63;
  const int wm = (w >> 1) * 64, wn = (w & 1) * 64;
  const int l16 = lane & 15, qd = lane >> 4;

  f32x4 acc[4][4];
#pragma unroll
  for (int i = 0; i < 4; ++i)
#pragma unroll
    for (int j = 0; j < 4; ++j) acc[i][j] = (f32x4){0.f, 0.f, 0.f, 0.f};

  const int r0 = tid >> 2, c0 = (tid & 3) * 8;
  const int r1 = r0 + 64;

  for (int k0 = 0; k0 < Dz; k0 += 32) {
    __syncthreads();
    async16(&lA[r0][c0], A  + (size_t)(m0 + r0) * Dz + k0 + c0);
    async16(&lB[r0][c0], Bt + (size_t)(n0 + r0) * Dz + k0 + c0);
    async16(&lA[r1][c0], A  + (size_t)(m0 + r1) * Dz + k0 + c0);
    async16(&lB[r1][c0], Bt + (size_t)(n0 + r1) * Dz + k0 + c0);
    __syncthreads();
    bf16x8 af[4], bfv[4];
#pragma unroll
    for (int t = 0; t < 4; ++t) {
      af[t]  = *(const bf16x8*)&lA[wm + t * 16 + l16][qd * 8];
      bfv[t] = *(const bf16x8*)&lB[wn + t * 16 + l16][qd * 8];
    }
#pragma unroll
    for (int mt = 0; mt < 4; ++mt)
#pragma unroll
      for (int nt = 0; nt < 4; ++nt)
        acc[mt][nt] = __builtin_amdgcn_mfma_f32_16x16x32_bf16(af[mt], bfv[nt], acc[mt][nt], 0, 0, 0);
  }

#pragma unroll
  for (int nt = 0; nt < 4; ++nt) {
    const int n = n0 + wn + nt * 16 + l16;
    const float bvl = bias[n];
#pragma unroll
    for (int mt = 0; mt < 4; ++mt)
#pragma unroll
      for (int r = 0; r < 4; ++r) {
        const int m = m0 + wm + mt * 16 + qd * 4 + r;
        Cv[(size_t)m * Dz + n] = f2bf((acc[mt][nt][r] + bvl) * cs);
      }
  }
}

// -------- FC GEMM: 128(M)x64(N) tile for 2 blocks/CU at N=1024, fp32 out --------
__global__ void __launch_bounds__(256)
gemm_fc(const u16* __restrict__ A, const u16* __restrict__ Bt,
        const float* __restrict__ bias, float* __restrict__ C)
{
  __shared__ __align__(16) u16 lA[128][32];
  __shared__ __align__(16) u16 lB[64][32];
  const int m0 = blockIdx.y * 128, n0 = blockIdx.x * 64;
  const int tid = threadIdx.x;
  const int w = tid >> 6, lane = tid & 63;
  const int wm = (w >> 1) * 64, wn = (w & 1) * 32;
  const int l16 = lane & 15, qd = lane >> 4;

  f32x4 acc[4][2];
#pragma unroll
  for (int i = 0; i < 4; ++i)
#pragma unroll
    for (int j = 0; j < 2; ++j) acc[i][j] = (f32x4){0.f, 0.f, 0.f, 0.f};

  const int r0 = tid >> 2, c0 = (tid & 3) * 8;

  for (int k0 = 0; k0 < Dz; k0 += 32) {
    __syncthreads();
    async16(&lA[r0][c0],      A  + (size_t)(m0 + r0) * Dz + k0 + c0);
    async16(&lA[r0 + 64][c0], A  + (size_t)(m0 + r0 + 64) * Dz + k0 + c0);
    async16(&lB[r0][c0],      Bt + (size_t)(n0 + r0) * Dz + k0 + c0);
    __syncthreads();
    bf16x8 af[4], bfv[2];
#pragma unroll
    for (int t = 0; t < 4; ++t)
      af[t] = *(const bf16x8*)&lA[wm + t * 16 + l16][qd * 8];
#pragma unroll
    for (int t = 0; t < 2; ++t)
      bfv[t] = *(const bf16x8*)&lB[wn + t * 16 + l16][qd * 8];
#pragma unroll
    for (int mt = 0; mt < 4; ++mt)
#pragma unroll
      for (int nt = 0; nt < 2; ++nt)
        acc[mt][nt] = __builtin_amdgcn_mfma_f32_16x16x32_bf16(af[mt], bfv[nt], acc[mt][nt], 0, 0, 0);
  }

#pragma unroll
  for (int nt = 0; nt < 2; ++nt) {
    const int n = n0 + wn + nt * 16 + l16;
    const float bvl = bias[n];
#pragma unroll
    for (int mt = 0; mt < 4; ++mt)
#pragma unroll
      for (int r = 0; r < 4; ++r) {
        const int m = m0 + wm + mt * 16 + qd * 4 + r;
        C[(size_t)m * Dz + n] = acc[mt][nt][r] + bvl;
      }
  }
}

// ---------------- fused flash-style attention (shift-0 softmax) ----------------
// grid (S/128, B*H), block 512 = 8 waves; wave w owns q-rows [w*16, w*16+16).
// vs R4: (1) K/V double-buffered in LDS -> ONE barrier per kv-tile; (2) V columns
// perm'd (see vtrans) so PV V-fragments are b128 reads with conflict-free 8-lane
// phases (R4's b64 reads were 2-way conflicted: 12.58M conflict cycles).
// Algorithm otherwise identical to proven R3/R4: swapped QK^T (st = mfma_16x16x32
// (K_frag, Q_frag) -> lane (l16,qd) reg r = score(q=l16, s=nt*16+qd*4+r)); P = exp2
// in-register; that quad IS the A-frag of mfma_f32_16x16x16bf16_1k for PV.
__global__ void __launch_bounds__(512, 4)
attn_kernel(const u16* __restrict__ Qp, const u16* __restrict__ Kp,
            const u16* __restrict__ Vt, u16* __restrict__ Ao)
{
  __shared__ __align__(16) u16 lK[2][128][72];  // stride 144 B; 2x 18 KB
  __shared__ __align__(16) u16 lV[2][64][136];  // stride 272 B; 2x 17.4 KB (71.6 KB tot)

  const int q0 = blockIdx.x * 128;
  const int bh = blockIdx.y;
  const int b = bh >> 4, h = bh & 15;
  const int tid = threadIdx.x, w = tid >> 6, lane = tid & 63;
  const int l16 = lane & 15, qd = lane >> 4;

  const int krow = tid >> 3, kcol = (tid & 7) * 8;    // + p*64 rows (krow 0..63)
  const int vrow = tid >> 4, vcol = (tid & 15) * 8;   // + p*32 rows (vrow 0..31)

  // prefetch tile 0 into registers
  u16x8 kreg[2], vreg[2];
#pragma unroll
  for (int p = 0; p < 2; ++p) {
    kreg[p] = *(const u16x8*)(Kp + (size_t)(b * Sz + p * 64 + krow) * Dz + h * 64 + kcol);
    vreg[p] = *(const u16x8*)(Vt + (size_t)(bh * 64 + p * 32 + vrow) * Sz + vcol);
  }

  // Q fragments in registers (pre-scaled by C1), reused for all kv tiles
  bf16x8 qf[2];
#pragma unroll
  for (int ks = 0; ks < 2; ++ks)
    qf[ks] = *(const bf16x8*)(Qp + (size_t)(b * Sz + q0 + w * 16 + l16) * Dz
                              + h * 64 + ks * 32 + qd * 8);

  f32x4 oacc[4];
#pragma unroll
  for (int j = 0; j < 4; ++j) oacc[j] = (f32x4){0.f, 0.f, 0.f, 0.f};
  float lsum = 0.f;

  for (int t = 0; t < Sz / 128; ++t) {
    const int cur = t & 1;
    // stage tile t into buf[cur] (other waves may still be computing buf[cur^1])
#pragma unroll
    for (int p = 0; p < 2; ++p) {
      *(u16x8*)&lK[cur][p * 64 + krow][kcol] = kreg[p];
      *(u16x8*)&lV[cur][p * 32 + vrow][vcol] = vreg[p];
    }
    if (t + 1 < Sz / 128) {
      const int kv = (t + 1) * 128;
#pragma unroll
      for (int p = 0; p < 2; ++p) {
        kreg[p] = *(const u16x8*)(Kp + (size_t)(b * Sz + kv + p * 64 + krow) * Dz + h * 64 + kcol);
        vreg[p] = *(const u16x8*)(Vt + (size_t)(bh * 64 + p * 32 + vrow) * Sz + kv + vcol);
      }
    }
    __syncthreads();   // single barrier: buf[cur] writes visible; prev-tile reads done

    // per strip-pair: S^T = K @ Q^T ; P = exp2 in-register ; O += P @ V ; lsum += sum(P)
#pragma unroll
    for (int hf = 0; hf < 2; ++hf)
#pragma unroll
      for (int np = 0; np < 2; ++np) {
        const int ntA = hf * 4 + np * 2, ntB = ntA + 1;
        const bf16x8 kA0 = *(const bf16x8*)&lK[cur][ntA * 16 + l16][qd * 8];
        const bf16x8 kA1 = *(const bf16x8*)&lK[cur][ntA * 16 + l16][32 + qd * 8];
        const bf16x8 kB0 = *(const bf16x8*)&lK[cur][ntB * 16 + l16][qd * 8];
        const bf16x8 kB1 = *(const bf16x8*)&lK[cur][ntB * 16 + l16][32 + qd * 8];
        f32x4 stA = (f32x4){0.f, 0.f, 0.f, 0.f};
        f32x4 stB = (f32x4){0.f, 0.f, 0.f, 0.f};
        stA = __builtin_amdgcn_mfma_f32_16x16x32_bf16(kA0, qf[0], stA, 0, 0, 0);
        stA = __builtin_amdgcn_mfma_f32_16x16x32_bf16(kA1, qf[1], stA, 0, 0, 0);
        stB = __builtin_amdgcn_mfma_f32_16x16x32_bf16(kB0, qf[0], stB, 0, 0, 0);
        stB = __builtin_amdgcn_mfma_f32_16x16x32_bf16(kB1, qf[1], stB, 0, 0, 0);

        const float a0 = exp2f(stA[0]), a1 = exp2f(stA[1]);
        const float a2 = exp2f(stA[2]), a3 = exp2f(stA[3]);
        const float b0 = exp2f(stB[0]), b1 = exp2f(stB[1]);
        const float b2 = exp2f(stB[2]), b3 = exp2f(stB[3]);
        lsum += ((a0 + a1) + (a2 + a3)) + ((b0 + b1) + (b2 + b3));
        bf16x4 pA, pB;
        pA[0] = (__bf16)a0; pA[1] = (__bf16)a1; pA[2] = (__bf16)a2; pA[3] = (__bf16)a3;
        pB[0] = (__bf16)b0; pB[1] = (__bf16)b1; pB[2] = (__bf16)b2; pB[3] = (__bf16)b3;
        const s16x4 pfA = __builtin_bit_cast(s16x4, pA);
        const s16x4 pfB = __builtin_bit_cast(s16x4, pB);

#pragma unroll
        for (int nd = 0; nd < 4; ++nd) {
          // perm'd V: one b128 = strips {ntA, ntB} at this qd (conflict-free phases)
          const u16x8 v2 = *(const u16x8*)&lV[cur][nd * 16 + l16][hf * 64 + qd * 16 + np * 8];
          const s16x4 vlo = {(short)v2[0], (short)v2[1], (short)v2[2], (short)v2[3]};
          const s16x4 vhi = {(short)v2[4], (short)v2[5], (short)v2[6], (short)v2[7]};
          oacc[nd] = __builtin_amdgcn_mfma_f32_16x16x16bf16_1k(pfA, vlo, oacc[nd], 0, 0, 0);
          oacc[nd] = __builtin_amdgcn_mfma_f32_16x16x16bf16_1k(pfB, vhi, oacc[nd], 0, 0, 0);
        }
      }
  }

  // rowsum finalize: lane (l16,qd) holds partial for q=l16 over its s-quads;
  // reduce across the 4 qd-groups, then fetch rowsum(q=qd*4+r) for the store rows.
  lsum += __shfl_xor(lsum, 16, 64);
  lsum += __shfl_xor(lsum, 32, 64);

  // normalize + store (oacc reg r holds q-row qd*4+r, col = h*64 + nd*16 + l16)
#pragma unroll
  for (int r = 0; r < 4; ++r) {
    const float inv = 1.0f / __shfl(lsum, qd * 4 + r, 64);
    const int row = q0 + w * 16 + qd * 4 + r;
#pragma unroll
    for (int nd = 0; nd < 4; ++nd) {
      const int col = h * 64 + nd * 16 + l16;
      Ao[(size_t)(b * Sz + row) * Dz + col] = f2bf(oacc[nd][r] * inv);
    }
  }
}

// ---------------- host launch ----------------
extern "C" void kernel_launch(void* const* d_in, const int* in_sizes, int n_in,
                              void* d_out, int out_size, void* d_ws, size_t ws_size,
                              hipStream_t stream) {
  const float* query = (const float*)d_in[0];
  const float* key   = (const float*)d_in[1];
  const float* value = (const float*)d_in[2];
  const float* w_q  = (const float*)d_in[3];
  const float* b_q  = (const float*)d_in[4];
  const float* w_k  = (const float*)d_in[5];
  const float* b_k  = (const float*)d_in[6];
  const float* w_v  = (const float*)d_in[7];
  const float* b_v  = (const float*)d_in[8];
  const float* w_fc = (const float*)d_in[9];
  const float* b_fc = (const float*)d_in[10];
  float* out = (float*)d_out;

  const size_t XE = (size_t)Mz * Dz;   // 4 Mi elements
  const size_t WE = (size_t)Dz * Dz;   // 1 Mi elements
  u16* Xq  = (u16*)d_ws;               // bf16 inputs
  u16* Xk  = Xq + XE;
  u16* Xv  = Xk + XE;
  u16* Wt  = Xv + XE;                  // 4 stacked transposed weights [N][K]: q,k,v,fc
  u16* Wtf = Wt + 3 * WE;
  u16* Qp  = Wt + 4 * WE;              // projections
  u16* Kp  = Qp + XE;
  u16* Vp  = Kp + XE;
  u16* Vt  = Xk;                       // reuse: Xk dead after QKV projections
  u16* Ao  = Xq;                       // reuse: Xq dead after QKV projections

  const int n4 = (int)(XE / 4);
  cvt3_kernel<<<dim3(n4 / 256, 3), 256, 0, stream>>>(query, key, value, Xq, Xk, Xv, n4);

  wt_cvt_kernel<<<dim3(Dz / 32, Dz / 32, 4), dim3(32, 8), 0, stream>>>(w_q, w_k, w_v, w_fc, Wt);

  gemm_qkv<<<dim3(24, Mz / 128), 256, 0, stream>>>(Xq, Xk, Xv, Wt, b_q, b_k, b_v, Qp, Kp, Vp);

  vtrans_kernel<<<dim3(Sz / 64, Bz * Hz), 256, 0, stream>>>(Vp, Vt);

  attn_kernel<<<dim3(Sz / 128, Bz * Hz), 512, 0, stream>>>(Qp, Kp, Vt, Ao);

  gemm_fc<<<dim3(Dz / 64, Mz / 128), 256, 0, stream>>>(Ao, Wtf, b_fc, out);
}

// Round 6
// 255.957 us; speedup vs baseline: 1.0154x; 1.0154x over previous
//
#include <hip/hip_runtime.h>
#include <stdint.h>

#define Bz 2
#define Sz 2048
#define Dz 1024
#define Hz 16
#define HDz 64
#define Mz (Bz*Sz)   // 4096

typedef unsigned short u16;
typedef __attribute__((ext_vector_type(8))) __bf16 bf16x8;
typedef __attribute__((ext_vector_type(4))) __bf16 bf16x4;
typedef __attribute__((ext_vector_type(8))) unsigned short u16x8;
typedef __attribute__((ext_vector_type(4))) float f32x4;
typedef __attribute__((ext_vector_type(4))) short s16x4;

#define C1 0.1803368801111243f   /* 0.125 * log2(e) */

__device__ __forceinline__ u16 f2bf(float f) {
  union { float f; unsigned u; } v; v.f = f;
  unsigned r = v.u + 0x7fffu + ((v.u >> 16) & 1u);
  return (u16)(r >> 16);
}

__device__ __forceinline__ void async16(void* lds, const void* g) {
  __builtin_amdgcn_global_load_lds(
      (const __attribute__((address_space(1))) unsigned int*)g,
      (__attribute__((address_space(3))) unsigned int*)lds, 16, 0, 0);
}

// ---------- merged preproc: grid.y 0..2 = fp32->bf16 q/k/v; 3..6 = weight T+cvt ----------
__global__ void __launch_bounds__(256)
prep_kernel(const float* __restrict__ q, const float* __restrict__ k,
            const float* __restrict__ v,
            const float* __restrict__ w0, const float* __restrict__ w1,
            const float* __restrict__ w2, const float* __restrict__ w3,
            u16* __restrict__ xq, u16* __restrict__ xk, u16* __restrict__ xv,
            u16* __restrict__ Wt, int n4) {
  __shared__ __align__(16) float t[32][33];
  const int role = blockIdx.y;
  if (role < 3) {
    const float* in = role == 0 ? q : role == 1 ? k : v;
    u16* out = role == 0 ? xq : role == 1 ? xk : xv;
    int i = blockIdx.x * 256 + threadIdx.x;
    if (i < n4) {
      float4 f = ((const float4*)in)[i];
      ((ushort4*)out)[i] = make_ushort4(f2bf(f.x), f2bf(f.y), f2bf(f.z), f2bf(f.w));
    }
  } else {
    if (blockIdx.x >= (Dz / 32) * (Dz / 32)) return;
    const int z = role - 3;
    const float* W = z == 0 ? w0 : z == 1 ? w1 : z == 2 ? w2 : w3;
    u16* o = Wt + (size_t)z * Dz * Dz;
    const int n0 = (blockIdx.x & 31) * 32, k0 = (blockIdx.x >> 5) * 32;
    const int x = threadIdx.x & 31, y = threadIdx.x >> 5;   // (32,8)
#pragma unroll
    for (int i = 0; i < 4; ++i)
      t[y + i*8][x] = W[(size_t)(k0 + y + i*8) * Dz + n0 + x];
    __syncthreads();
#pragma unroll
    for (int i = 0; i < 4; ++i)
      o[(size_t)(n0 + y + i*8) * Dz + k0 + x] = f2bf(t[x][y + i*8]);
  }
}

// -------- fused QKV GEMM: 128x128 tile; blockIdx.x>>3 selects {Q,K,V} --------
// Q output pre-scaled by C1 (= 1/sqrt(HD)*log2e) so attn softmax is pure exp2.
// sel==2 (V) writes DIRECTLY in Vt[bh][d][s] layout (the transform old vtrans did):
// per thread, acc[mt][nt][r] = Vproj[m0+wm+mt*16+qd*4+r][n0+wn+nt*16+l16]; for fixed
// (mt,nt) the 4 regs are 4 consecutive s at one (h,d) -> one ushort4 store.
__global__ void __launch_bounds__(256)
gemm_qkv(const u16* __restrict__ xq, const u16* __restrict__ xk, const u16* __restrict__ xv,
         const u16* __restrict__ Wt3,
         const float* __restrict__ bq, const float* __restrict__ bk, const float* __restrict__ bv,
         u16* __restrict__ Qp, u16* __restrict__ Kp, u16* __restrict__ Vt)
{
  __shared__ __align__(16) u16 lA[128][32];
  __shared__ __align__(16) u16 lB[128][32];
  const int sel = blockIdx.x >> 3;
  const int n0 = (blockIdx.x & 7) * 128;
  const int m0 = blockIdx.y * 128;
  const u16* A = sel == 0 ? xq : sel == 1 ? xk : xv;
  const u16* Bt = Wt3 + (size_t)sel * Dz * Dz;
  const float* bias = sel == 0 ? bq : sel == 1 ? bk : bv;
  const float cs = sel == 0 ? C1 : 1.0f;

  const int tid = threadIdx.x;
  const int w = tid >> 6, lane = tid & 63;
  const int wm = (w >> 1) * 64, wn = (w & 1) * 64;
  const int l16 = lane & 15, qd = lane >> 4;

  f32x4 acc[4][4];
#pragma unroll
  for (int i = 0; i < 4; ++i)
#pragma unroll
    for (int j = 0; j < 4; ++j) acc[i][j] = (f32x4){0.f, 0.f, 0.f, 0.f};

  const int r0 = tid >> 2, c0 = (tid & 3) * 8;
  const int r1 = r0 + 64;

  for (int k0 = 0; k0 < Dz; k0 += 32) {
    __syncthreads();
    async16(&lA[r0][c0], A  + (size_t)(m0 + r0) * Dz + k0 + c0);
    async16(&lB[r0][c0], Bt + (size_t)(n0 + r0) * Dz + k0 + c0);
    async16(&lA[r1][c0], A  + (size_t)(m0 + r1) * Dz + k0 + c0);
    async16(&lB[r1][c0], Bt + (size_t)(n0 + r1) * Dz + k0 + c0);
    __syncthreads();
    bf16x8 af[4], bfv[4];
#pragma unroll
    for (int t = 0; t < 4; ++t) {
      af[t]  = *(const bf16x8*)&lA[wm + t * 16 + l16][qd * 8];
      bfv[t] = *(const bf16x8*)&lB[wn + t * 16 + l16][qd * 8];
    }
#pragma unroll
    for (int mt = 0; mt < 4; ++mt)
#pragma unroll
      for (int nt = 0; nt < 4; ++nt)
        acc[mt][nt] = __builtin_amdgcn_mfma_f32_16x16x32_bf16(af[mt], bfv[nt], acc[mt][nt], 0, 0, 0);
  }

  if (sel < 2) {
    u16* Cv = sel == 0 ? Qp : Kp;
#pragma unroll
    for (int nt = 0; nt < 4; ++nt) {
      const int n = n0 + wn + nt * 16 + l16;
      const float bvl = bias[n];
#pragma unroll
      for (int mt = 0; mt < 4; ++mt)
#pragma unroll
        for (int r = 0; r < 4; ++r) {
          const int m = m0 + wm + mt * 16 + qd * 4 + r;
          Cv[(size_t)m * Dz + n] = f2bf((acc[mt][nt][r] + bvl) * cs);
        }
    }
  } else {
    const int bb = m0 >> 11;                 // batch (Sz = 2048)
    const int sb = (m0 & (Sz - 1)) + wm;     // s-base for this wave
#pragma unroll
    for (int nt = 0; nt < 4; ++nt) {
      const int n = n0 + wn + nt * 16 + l16;
      const float bvl = bias[n];
      const int h2 = n >> 6, d2 = n & 63;
      u16* dst = Vt + ((size_t)((bb * 16 + h2) * 64 + d2)) * Sz + sb;
#pragma unroll
      for (int mt = 0; mt < 4; ++mt) {
        const int s = mt * 16 + qd * 4;
        ushort4 pk = make_ushort4(f2bf(acc[mt][nt][0] + bvl), f2bf(acc[mt][nt][1] + bvl),
                                  f2bf(acc[mt][nt][2] + bvl), f2bf(acc[mt][nt][3] + bvl));
        *(ushort4*)(dst + s) = pk;
      }
    }
  }
}

// -------- FC GEMM: 128(M)x64(N) tile for 2 blocks/CU at N=1024, fp32 out --------
__global__ void __launch_bounds__(256)
gemm_fc(const u16* __restrict__ A, const u16* __restrict__ Bt,
        const float* __restrict__ bias, float* __restrict__ C)
{
  __shared__ __align__(16) u16 lA[128][32];
  __shared__ __align__(16) u16 lB[64][32];
  const int m0 = blockIdx.y * 128, n0 = blockIdx.x * 64;
  const int tid = threadIdx.x;
  const int w = tid >> 6, lane = tid & 63;
  const int wm = (w >> 1) * 64, wn = (w & 1) * 32;
  const int l16 = lane & 15, qd = lane >> 4;

  f32x4 acc[4][2];
#pragma unroll
  for (int i = 0; i < 4; ++i)
#pragma unroll
    for (int j = 0; j < 2; ++j) acc[i][j] = (f32x4){0.f, 0.f, 0.f, 0.f};

  const int r0 = tid >> 2, c0 = (tid & 3) * 8;

  for (int k0 = 0; k0 < Dz; k0 += 32) {
    __syncthreads();
    async16(&lA[r0][c0],      A  + (size_t)(m0 + r0) * Dz + k0 + c0);
    async16(&lA[r0 + 64][c0], A  + (size_t)(m0 + r0 + 64) * Dz + k0 + c0);
    async16(&lB[r0][c0],      Bt + (size_t)(n0 + r0) * Dz + k0 + c0);
    __syncthreads();
    bf16x8 af[4], bfv[2];
#pragma unroll
    for (int t = 0; t < 4; ++t)
      af[t] = *(const bf16x8*)&lA[wm + t * 16 + l16][qd * 8];
#pragma unroll
    for (int t = 0; t < 2; ++t)
      bfv[t] = *(const bf16x8*)&lB[wn + t * 16 + l16][qd * 8];
#pragma unroll
    for (int mt = 0; mt < 4; ++mt)
#pragma unroll
      for (int nt = 0; nt < 2; ++nt)
        acc[mt][nt] = __builtin_amdgcn_mfma_f32_16x16x32_bf16(af[mt], bfv[nt], acc[mt][nt], 0, 0, 0);
  }

#pragma unroll
  for (int nt = 0; nt < 2; ++nt) {
    const int n = n0 + wn + nt * 16 + l16;
    const float bvl = bias[n];
#pragma unroll
    for (int mt = 0; mt < 4; ++mt)
#pragma unroll
      for (int r = 0; r < 4; ++r) {
        const int m = m0 + wm + mt * 16 + qd * 4 + r;
        C[(size_t)m * Dz + n] = acc[mt][nt][r] + bvl;
      }
  }
}

// ---------------- fused flash-style attention (shift-0 softmax) ----------------
// EXACT R4 kernel (proven 74.1 us). grid (S/128, B*H), block 512 = 8 waves; wave w
// owns q-rows [w*16, w*16+16). Swapped QK^T (st = mfma_16x16x32(K_frag, Q_frag) ->
// lane (l16,qd) reg r = score(q=l16, s=nt*16+qd*4+r)); P = exp2 in-register; that
// quad IS the A-frag of mfma_f32_16x16x16bf16_1k for PV. Row sums on VALU with a
// shfl-reduce epilogue.
__global__ void __launch_bounds__(512, 4)
attn_kernel(const u16* __restrict__ Qp, const u16* __restrict__ Kp,
            const u16* __restrict__ Vt, u16* __restrict__ Ao)
{
  __shared__ __align__(16) u16 lK[128][72];     // stride 144 B (≡16 mod 128)
  __shared__ __align__(16) u16 lV[64][136];     // stride 272 B (≡16 mod 128)

  const int q0 = blockIdx.x * 128;
  const int bh = blockIdx.y;
  const int b = bh >> 4, h = bh & 15;
  const int tid = threadIdx.x, w = tid >> 6, lane = tid & 63;
  const int l16 = lane & 15, qd = lane >> 4;

  const int krow = tid >> 3, kcol = (tid & 7) * 8;    // + p*64 rows (krow 0..63)
  const int vrow = tid >> 4, vcol = (tid & 15) * 8;   // + p*32 rows (vrow 0..31)

  // prefetch tile 0 into registers
  u16x8 kreg[2], vreg[2];
#pragma unroll
  for (int p = 0; p < 2; ++p) {
    kreg[p] = *(const u16x8*)(Kp + (size_t)(b * Sz + p * 64 + krow) * Dz + h * 64 + kcol);
    vreg[p] = *(const u16x8*)(Vt + (size_t)(bh * 64 + p * 32 + vrow) * Sz + vcol);
  }

  // Q fragments in registers (pre-scaled by C1), reused for all kv tiles
  bf16x8 qf[2];
#pragma unroll
  for (int ks = 0; ks < 2; ++ks)
    qf[ks] = *(const bf16x8*)(Qp + (size_t)(b * Sz + q0 + w * 16 + l16) * Dz
                              + h * 64 + ks * 32 + qd * 8);

  f32x4 oacc[4];
#pragma unroll
  for (int j = 0; j < 4; ++j) oacc[j] = (f32x4){0.f, 0.f, 0.f, 0.f};
  float lsum = 0.f;

  for (int t = 0; t < Sz / 128; ++t) {
    __syncthreads();
#pragma unroll
    for (int p = 0; p < 2; ++p) {
      *(u16x8*)&lK[p * 64 + krow][kcol] = kreg[p];
      *(u16x8*)&lV[p * 32 + vrow][vcol] = vreg[p];
    }
    if (t + 1 < Sz / 128) {
      const int kv = (t + 1) * 128;
#pragma unroll
      for (int p = 0; p < 2; ++p) {
        kreg[p] = *(const u16x8*)(Kp + (size_t)(b * Sz + kv + p * 64 + krow) * Dz + h * 64 + kcol);
        vreg[p] = *(const u16x8*)(Vt + (size_t)(bh * 64 + p * 32 + vrow) * Sz + kv + vcol);
      }
    }
    __syncthreads();

    // per 16-s strip: S^T = K @ Q^T ; P = exp2 in-register ; O += P @ V ; lsum += sum(P)
#pragma unroll
    for (int nt = 0; nt < 8; ++nt) {
      const bf16x8 kf0 = *(const bf16x8*)&lK[nt * 16 + l16][qd * 8];
      const bf16x8 kf1 = *(const bf16x8*)&lK[nt * 16 + l16][32 + qd * 8];
      f32x4 st = (f32x4){0.f, 0.f, 0.f, 0.f};
      st = __builtin_amdgcn_mfma_f32_16x16x32_bf16(kf0, qf[0], st, 0, 0, 0);
      st = __builtin_amdgcn_mfma_f32_16x16x32_bf16(kf1, qf[1], st, 0, 0, 0);
      const float e0 = exp2f(st[0]), e1 = exp2f(st[1]);
      const float e2 = exp2f(st[2]), e3 = exp2f(st[3]);
      lsum += (e0 + e1) + (e2 + e3);
      bf16x4 pb;
      pb[0] = (__bf16)e0; pb[1] = (__bf16)e1; pb[2] = (__bf16)e2; pb[3] = (__bf16)e3;
      const s16x4 pf = __builtin_bit_cast(s16x4, pb);
#pragma unroll
      for (int nd = 0; nd < 4; ++nd) {
        const s16x4 vf = *(const s16x4*)&lV[nd * 16 + l16][nt * 16 + qd * 4];
        oacc[nd] = __builtin_amdgcn_mfma_f32_16x16x16bf16_1k(pf, vf, oacc[nd], 0, 0, 0);
      }
    }
  }

  // rowsum finalize: lane (l16,qd) holds partial for q=l16 over its s-quads;
  // reduce across the 4 qd-groups, then fetch rowsum(q=qd*4+r) for the store rows.
  lsum += __shfl_xor(lsum, 16, 64);
  lsum += __shfl_xor(lsum, 32, 64);

  // normalize + store (oacc reg r holds q-row qd*4+r, col = h*64 + nd*16 + l16)
#pragma unroll
  for (int r = 0; r < 4; ++r) {
    const float inv = 1.0f / __shfl(lsum, qd * 4 + r, 64);
    const int row = q0 + w * 16 + qd * 4 + r;
#pragma unroll
    for (int nd = 0; nd < 4; ++nd) {
      const int col = h * 64 + nd * 16 + l16;
      Ao[(size_t)(b * Sz + row) * Dz + col] = f2bf(oacc[nd][r] * inv);
    }
  }
}

// ---------------- host launch ----------------
extern "C" void kernel_launch(void* const* d_in, const int* in_sizes, int n_in,
                              void* d_out, int out_size, void* d_ws, size_t ws_size,
                              hipStream_t stream) {
  const float* query = (const float*)d_in[0];
  const float* key   = (const float*)d_in[1];
  const float* value = (const float*)d_in[2];
  const float* w_q  = (const float*)d_in[3];
  const float* b_q  = (const float*)d_in[4];
  const float* w_k  = (const float*)d_in[5];
  const float* b_k  = (const float*)d_in[6];
  const float* w_v  = (const float*)d_in[7];
  const float* b_v  = (const float*)d_in[8];
  const float* w_fc = (const float*)d_in[9];
  const float* b_fc = (const float*)d_in[10];
  float* out = (float*)d_out;

  const size_t XE = (size_t)Mz * Dz;   // 4 Mi elements
  const size_t WE = (size_t)Dz * Dz;   // 1 Mi elements
  u16* Xq  = (u16*)d_ws;               // bf16 inputs
  u16* Xk  = Xq + XE;
  u16* Xv  = Xk + XE;
  u16* Wt  = Xv + XE;                  // 4 stacked transposed weights [N][K]: q,k,v,fc
  u16* Wtf = Wt + 3 * WE;
  u16* Qp  = Wt + 4 * WE;              // projections
  u16* Kp  = Qp + XE;
  u16* Vt  = Kp + XE;                  // V written transposed [bh][d][s] by gemm_qkv
                                       // (NOT aliasing Xk: gemm_qkv reads Xk concurrently)
  u16* Ao  = Xq;                       // reuse: Xq dead after QKV projections

  const int n4 = (int)(XE / 4);
  prep_kernel<<<dim3(n4 / 256, 7), 256, 0, stream>>>(query, key, value,
                                                     w_q, w_k, w_v, w_fc,
                                                     Xq, Xk, Xv, Wt, n4);

  gemm_qkv<<<dim3(24, Mz / 128), 256, 0, stream>>>(Xq, Xk, Xv, Wt, b_q, b_k, b_v, Qp, Kp, Vt);

  attn_kernel<<<dim3(Sz / 128, Bz * Hz), 512, 0, stream>>>(Qp, Kp, Vt, Ao);

  gemm_fc<<<dim3(Dz / 64, Mz / 128), 256, 0, stream>>>(Ao, Wtf, b_fc, out);
}

// Round 7
// 255.950 us; speedup vs baseline: 1.0154x; 1.0000x over previous
//
#include <hip/hip_runtime.h>
#include <stdint.h>

#define Bz 2
#define Sz 2048
#define Dz 1024
#define Hz 16
#define HDz 64
#define Mz (Bz*Sz)   // 4096

typedef unsigned short u16;
typedef __attribute__((ext_vector_type(8))) __bf16 bf16x8;
typedef __attribute__((ext_vector_type(4))) __bf16 bf16x4;
typedef __attribute__((ext_vector_type(8))) unsigned short u16x8;
typedef __attribute__((ext_vector_type(4))) unsigned short u16x4;
typedef __attribute__((ext_vector_type(4))) float f32x4;
typedef __attribute__((ext_vector_type(4))) short s16x4;

#define C1 0.1803368801111243f   /* 0.125 * log2(e) */

__device__ __forceinline__ u16 f2bf(float f) {
  union { float f; unsigned u; } v; v.f = f;
  unsigned r = v.u + 0x7fffu + ((v.u >> 16) & 1u);
  return (u16)(r >> 16);
}

__device__ __forceinline__ void async16(void* lds, const void* g) {
  __builtin_amdgcn_global_load_lds(
      (const __attribute__((address_space(1))) unsigned int*)g,
      (__attribute__((address_space(3))) unsigned int*)lds, 16, 0, 0);
}

// ---------- merged preproc: grid.y 0..2 = fp32->bf16 q/k/v; 3..6 = weight T+cvt ----------
__global__ void __launch_bounds__(256)
prep_kernel(const float* __restrict__ q, const float* __restrict__ k,
            const float* __restrict__ v,
            const float* __restrict__ w0, const float* __restrict__ w1,
            const float* __restrict__ w2, const float* __restrict__ w3,
            u16* __restrict__ xq, u16* __restrict__ xk, u16* __restrict__ xv,
            u16* __restrict__ Wt, int n4) {
  __shared__ __align__(16) float t[32][33];
  const int role = blockIdx.y;
  if (role < 3) {
    const float* in = role == 0 ? q : role == 1 ? k : v;
    u16* out = role == 0 ? xq : role == 1 ? xk : xv;
    int i = blockIdx.x * 256 + threadIdx.x;
    if (i < n4) {
      float4 f = ((const float4*)in)[i];
      ((ushort4*)out)[i] = make_ushort4(f2bf(f.x), f2bf(f.y), f2bf(f.z), f2bf(f.w));
    }
  } else {
    if (blockIdx.x >= (Dz / 32) * (Dz / 32)) return;
    const int z = role - 3;
    const float* W = z == 0 ? w0 : z == 1 ? w1 : z == 2 ? w2 : w3;
    u16* o = Wt + (size_t)z * Dz * Dz;
    const int n0 = (blockIdx.x & 31) * 32, k0 = (blockIdx.x >> 5) * 32;
    const int x = threadIdx.x & 31, y = threadIdx.x >> 5;   // (32,8)
#pragma unroll
    for (int i = 0; i < 4; ++i)
      t[y + i*8][x] = W[(size_t)(k0 + y + i*8) * Dz + n0 + x];
    __syncthreads();
#pragma unroll
    for (int i = 0; i < 4; ++i)
      o[(size_t)(n0 + y + i*8) * Dz + k0 + x] = f2bf(t[x][y + i*8]);
  }
}

// -------- fused QKV GEMM: 128x128 tile; blockIdx.x>>3 selects {Q,K,V} --------
// Q output pre-scaled by C1 (= 1/sqrt(HD)*log2e) so attn softmax is pure exp2.
// sel==2 (V): acc is transposed through an LDS patch (vt) so the Vt[bh][d][s] global
// stores are 256 B-contiguous per d-row (R6's direct 8 B scatter caused ~8x HBM write
// amplification: +10 us in gemm_qkv).
__global__ void __launch_bounds__(256)
gemm_qkv(const u16* __restrict__ xq, const u16* __restrict__ xk, const u16* __restrict__ xv,
         const u16* __restrict__ Wt3,
         const float* __restrict__ bq, const float* __restrict__ bk, const float* __restrict__ bv,
         u16* __restrict__ Qp, u16* __restrict__ Kp, u16* __restrict__ Vt)
{
  __shared__ __align__(16) u16 lA[128][32];
  __shared__ __align__(16) u16 lB[128][32];
  __shared__ __align__(16) u16 vt[64][136];   // sel==2 epilogue transpose patch
  const int sel = blockIdx.x >> 3;
  const int n0 = (blockIdx.x & 7) * 128;
  const int m0 = blockIdx.y * 128;
  const u16* A = sel == 0 ? xq : sel == 1 ? xk : xv;
  const u16* Bt = Wt3 + (size_t)sel * Dz * Dz;
  const float* bias = sel == 0 ? bq : sel == 1 ? bk : bv;
  const float cs = sel == 0 ? C1 : 1.0f;

  const int tid = threadIdx.x;
  const int w = tid >> 6, lane = tid & 63;
  const int wm = (w >> 1) * 64, wn = (w & 1) * 64;
  const int l16 = lane & 15, qd = lane >> 4;

  f32x4 acc[4][4];
#pragma unroll
  for (int i = 0; i < 4; ++i)
#pragma unroll
    for (int j = 0; j < 4; ++j) acc[i][j] = (f32x4){0.f, 0.f, 0.f, 0.f};

  const int r0 = tid >> 2, c0 = (tid & 3) * 8;
  const int r1 = r0 + 64;

  for (int k0 = 0; k0 < Dz; k0 += 32) {
    __syncthreads();
    async16(&lA[r0][c0], A  + (size_t)(m0 + r0) * Dz + k0 + c0);
    async16(&lB[r0][c0], Bt + (size_t)(n0 + r0) * Dz + k0 + c0);
    async16(&lA[r1][c0], A  + (size_t)(m0 + r1) * Dz + k0 + c0);
    async16(&lB[r1][c0], Bt + (size_t)(n0 + r1) * Dz + k0 + c0);
    __syncthreads();
    bf16x8 af[4], bfv[4];
#pragma unroll
    for (int t = 0; t < 4; ++t) {
      af[t]  = *(const bf16x8*)&lA[wm + t * 16 + l16][qd * 8];
      bfv[t] = *(const bf16x8*)&lB[wn + t * 16 + l16][qd * 8];
    }
#pragma unroll
    for (int mt = 0; mt < 4; ++mt)
#pragma unroll
      for (int nt = 0; nt < 4; ++nt)
        acc[mt][nt] = __builtin_amdgcn_mfma_f32_16x16x32_bf16(af[mt], bfv[nt], acc[mt][nt], 0, 0, 0);
  }

  if (sel < 2) {
    u16* Cv = sel == 0 ? Qp : Kp;
#pragma unroll
    for (int nt = 0; nt < 4; ++nt) {
      const int n = n0 + wn + nt * 16 + l16;
      const float bvl = bias[n];
#pragma unroll
      for (int mt = 0; mt < 4; ++mt)
#pragma unroll
        for (int r = 0; r < 4; ++r) {
          const int m = m0 + wm + mt * 16 + qd * 4 + r;
          Cv[(size_t)m * Dz + n] = f2bf((acc[mt][nt][r] + bvl) * cs);
        }
    }
  } else {
    const int bb = m0 >> 11;                 // batch (Sz = 2048)
    const int s0b = m0 & (Sz - 1);
#pragma unroll
    for (int P = 0; P < 2; ++P) {
      if (P) __syncthreads();                // vt reuse: phase-0 copies must be done
      if ((w & 1) == P) {                    // waves owning n-half [64P, 64P+64)
#pragma unroll
        for (int nt = 0; nt < 4; ++nt) {
          const int dn = nt * 16 + l16;      // local d-row
          const float bvl = bias[n0 + P * 64 + dn];
#pragma unroll
          for (int mt = 0; mt < 4; ++mt) {
            u16x4 qk = { f2bf(acc[mt][nt][0] + bvl), f2bf(acc[mt][nt][1] + bvl),
                         f2bf(acc[mt][nt][2] + bvl), f2bf(acc[mt][nt][3] + bvl) };
            *(u16x4*)&vt[dn][wm + mt * 16 + qd * 4] = qk;
          }
        }
      }
      __syncthreads();
      {
        const int dr = tid >> 2, sc = (tid & 3) * 32;
        const int n = n0 + P * 64 + dr;
        const int h2 = n >> 6, d2 = n & 63;
        u16* dst = Vt + ((size_t)((bb * 16 + h2) * 64 + d2)) * Sz + s0b + sc;
#pragma unroll
        for (int k2 = 0; k2 < 4; ++k2)
          *(u16x8*)(dst + k2 * 8) = *(const u16x8*)&vt[dr][sc + k2 * 8];
      }
    }
  }
}

// -------- FC GEMM: 128(M)x64(N) tile for 2 blocks/CU at N=1024, fp32 out --------
__global__ void __launch_bounds__(256)
gemm_fc(const u16* __restrict__ A, const u16* __restrict__ Bt,
        const float* __restrict__ bias, float* __restrict__ C)
{
  __shared__ __align__(16) u16 lA[128][32];
  __shared__ __align__(16) u16 lB[64][32];
  const int m0 = blockIdx.y * 128, n0 = blockIdx.x * 64;
  const int tid = threadIdx.x;
  const int w = tid >> 6, lane = tid & 63;
  const int wm = (w >> 1) * 64, wn = (w & 1) * 32;
  const int l16 = lane & 15, qd = lane >> 4;

  f32x4 acc[4][2];
#pragma unroll
  for (int i = 0; i < 4; ++i)
#pragma unroll
    for (int j = 0; j < 2; ++j) acc[i][j] = (f32x4){0.f, 0.f, 0.f, 0.f};

  const int r0 = tid >> 2, c0 = (tid & 3) * 8;

  for (int k0 = 0; k0 < Dz; k0 += 32) {
    __syncthreads();
    async16(&lA[r0][c0],      A  + (size_t)(m0 + r0) * Dz + k0 + c0);
    async16(&lA[r0 + 64][c0], A  + (size_t)(m0 + r0 + 64) * Dz + k0 + c0);
    async16(&lB[r0][c0],      Bt + (size_t)(n0 + r0) * Dz + k0 + c0);
    __syncthreads();
    bf16x8 af[4], bfv[2];
#pragma unroll
    for (int t = 0; t < 4; ++t)
      af[t] = *(const bf16x8*)&lA[wm + t * 16 + l16][qd * 8];
#pragma unroll
    for (int t = 0; t < 2; ++t)
      bfv[t] = *(const bf16x8*)&lB[wn + t * 16 + l16][qd * 8];
#pragma unroll
    for (int mt = 0; mt < 4; ++mt)
#pragma unroll
      for (int nt = 0; nt < 2; ++nt)
        acc[mt][nt] = __builtin_amdgcn_mfma_f32_16x16x32_bf16(af[mt], bfv[nt], acc[mt][nt], 0, 0, 0);
  }

#pragma unroll
  for (int nt = 0; nt < 2; ++nt) {
    const int n = n0 + wn + nt * 16 + l16;
    const float bvl = bias[n];
#pragma unroll
    for (int mt = 0; mt < 4; ++mt)
#pragma unroll
      for (int r = 0; r < 4; ++r) {
        const int m = m0 + wm + mt * 16 + qd * 4 + r;
        C[(size_t)m * Dz + n] = acc[mt][nt][r] + bvl;
      }
  }
}

// ---------------- fused flash-style attention (shift-0 softmax) ----------------
// R4 structure (proven 74 us) + lV XOR swizzle: V reads lV[row][col] with row stride
// 272 B (68 words ≡ 4 mod 32) put lanes l16 and l16+8 of each 16-lane b64 phase on
// the same banks (2-way, 12.58M conflict cycles). Swizzle col ^= ((row>>3)&1)<<2
// (lane-constant: row bit3 = l16/vrow bit3) -> banks {4*l16} ∪ {4*l16+2} = all 32.
// Staging splits the b128 V write into two b64s to apply the same involution.
__global__ void __launch_bounds__(512, 4)
attn_kernel(const u16* __restrict__ Qp, const u16* __restrict__ Kp,
            const u16* __restrict__ Vt, u16* __restrict__ Ao)
{
  __shared__ __align__(16) u16 lK[128][72];     // stride 144 B (≡16 mod 128)
  __shared__ __align__(16) u16 lV[64][136];     // stride 272 B, XOR-swizzled cols

  const int q0 = blockIdx.x * 128;
  const int bh = blockIdx.y;
  const int b = bh >> 4, h = bh & 15;
  const int tid = threadIdx.x, w = tid >> 6, lane = tid & 63;
  const int l16 = lane & 15, qd = lane >> 4;

  const int krow = tid >> 3, kcol = (tid & 7) * 8;    // + p*64 rows (krow 0..63)
  const int vrow = tid >> 4, vcol = (tid & 15) * 8;   // + p*32 rows (vrow 0..31)
  const int vswW = ((vrow >> 3) & 1) << 2;            // write-side swizzle (lane-const)
  const int vswR = ((l16 >> 3) & 1) << 2;             // read-side swizzle (lane-const)

  // prefetch tile 0 into registers
  u16x8 kreg[2], vreg[2];
#pragma unroll
  for (int p = 0; p < 2; ++p) {
    kreg[p] = *(const u16x8*)(Kp + (size_t)(b * Sz + p * 64 + krow) * Dz + h * 64 + kcol);
    vreg[p] = *(const u16x8*)(Vt + (size_t)(bh * 64 + p * 32 + vrow) * Sz + vcol);
  }

  // Q fragments in registers (pre-scaled by C1), reused for all kv tiles
  bf16x8 qf[2];
#pragma unroll
  for (int ks = 0; ks < 2; ++ks)
    qf[ks] = *(const bf16x8*)(Qp + (size_t)(b * Sz + q0 + w * 16 + l16) * Dz
                              + h * 64 + ks * 32 + qd * 8);

  f32x4 oacc[4];
#pragma unroll
  for (int j = 0; j < 4; ++j) oacc[j] = (f32x4){0.f, 0.f, 0.f, 0.f};
  float lsum = 0.f;

  for (int t = 0; t < Sz / 128; ++t) {
    __syncthreads();
#pragma unroll
    for (int p = 0; p < 2; ++p) {
      *(u16x8*)&lK[p * 64 + krow][kcol] = kreg[p];
      const u16x8 v = vreg[p];
      const u16x4 lo = {v[0], v[1], v[2], v[3]};
      const u16x4 hi = {v[4], v[5], v[6], v[7]};
      *(u16x4*)&lV[p * 32 + vrow][vcol ^ vswW]       = lo;
      *(u16x4*)&lV[p * 32 + vrow][(vcol + 4) ^ vswW] = hi;
    }
    if (t + 1 < Sz / 128) {
      const int kv = (t + 1) * 128;
#pragma unroll
      for (int p = 0; p < 2; ++p) {
        kreg[p] = *(const u16x8*)(Kp + (size_t)(b * Sz + kv + p * 64 + krow) * Dz + h * 64 + kcol);
        vreg[p] = *(const u16x8*)(Vt + (size_t)(bh * 64 + p * 32 + vrow) * Sz + kv + vcol);
      }
    }
    __syncthreads();

    // per 16-s strip: S^T = K @ Q^T ; P = exp2 in-register ; O += P @ V ; lsum += sum(P)
#pragma unroll
    for (int nt = 0; nt < 8; ++nt) {
      const bf16x8 kf0 = *(const bf16x8*)&lK[nt * 16 + l16][qd * 8];
      const bf16x8 kf1 = *(const bf16x8*)&lK[nt * 16 + l16][32 + qd * 8];
      f32x4 st = (f32x4){0.f, 0.f, 0.f, 0.f};
      st = __builtin_amdgcn_mfma_f32_16x16x32_bf16(kf0, qf[0], st, 0, 0, 0);
      st = __builtin_amdgcn_mfma_f32_16x16x32_bf16(kf1, qf[1], st, 0, 0, 0);
      const float e0 = exp2f(st[0]), e1 = exp2f(st[1]);
      const float e2 = exp2f(st[2]), e3 = exp2f(st[3]);
      lsum += (e0 + e1) + (e2 + e3);
      bf16x4 pb;
      pb[0] = (__bf16)e0; pb[1] = (__bf16)e1; pb[2] = (__bf16)e2; pb[3] = (__bf16)e3;
      const s16x4 pf = __builtin_bit_cast(s16x4, pb);
#pragma unroll
      for (int nd = 0; nd < 4; ++nd) {
        const s16x4 vf = *(const s16x4*)&lV[nd * 16 + l16][(nt * 16 + qd * 4) ^ vswR];
        oacc[nd] = __builtin_amdgcn_mfma_f32_16x16x16bf16_1k(pf, vf, oacc[nd], 0, 0, 0);
      }
    }
  }

  // rowsum finalize: lane (l16,qd) holds partial for q=l16 over its s-quads;
  // reduce across the 4 qd-groups, then fetch rowsum(q=qd*4+r) for the store rows.
  lsum += __shfl_xor(lsum, 16, 64);
  lsum += __shfl_xor(lsum, 32, 64);

  // normalize + store (oacc reg r holds q-row qd*4+r, col = h*64 + nd*16 + l16)
#pragma unroll
  for (int r = 0; r < 4; ++r) {
    const float inv = 1.0f / __shfl(lsum, qd * 4 + r, 64);
    const int row = q0 + w * 16 + qd * 4 + r;
#pragma unroll
    for (int nd = 0; nd < 4; ++nd) {
      const int col = h * 64 + nd * 16 + l16;
      Ao[(size_t)(b * Sz + row) * Dz + col] = f2bf(oacc[nd][r] * inv);
    }
  }
}

// ---------------- host launch ----------------
extern "C" void kernel_launch(void* const* d_in, const int* in_sizes, int n_in,
                              void* d_out, int out_size, void* d_ws, size_t ws_size,
                              hipStream_t stream) {
  const float* query = (const float*)d_in[0];
  const float* key   = (const float*)d_in[1];
  const float* value = (const float*)d_in[2];
  const float* w_q  = (const float*)d_in[3];
  const float* b_q  = (const float*)d_in[4];
  const float* w_k  = (const float*)d_in[5];
  const float* b_k  = (const float*)d_in[6];
  const float* w_v  = (const float*)d_in[7];
  const float* b_v  = (const float*)d_in[8];
  const float* w_fc = (const float*)d_in[9];
  const float* b_fc = (const float*)d_in[10];
  float* out = (float*)d_out;

  const size_t XE = (size_t)Mz * Dz;   // 4 Mi elements
  const size_t WE = (size_t)Dz * Dz;   // 1 Mi elements
  u16* Xq  = (u16*)d_ws;               // bf16 inputs
  u16* Xk  = Xq + XE;
  u16* Xv  = Xk + XE;
  u16* Wt  = Xv + XE;                  // 4 stacked transposed weights [N][K]: q,k,v,fc
  u16* Wtf = Wt + 3 * WE;
  u16* Qp  = Wt + 4 * WE;              // projections
  u16* Kp  = Qp + XE;
  u16* Vt  = Kp + XE;                  // V written transposed [bh][d][s] by gemm_qkv
  u16* Ao  = Xq;                       // reuse: Xq dead after QKV projections

  const int n4 = (int)(XE / 4);
  prep_kernel<<<dim3(n4 / 256, 7), 256, 0, stream>>>(query, key, value,
                                                     w_q, w_k, w_v, w_fc,
                                                     Xq, Xk, Xv, Wt, n4);

  gemm_qkv<<<dim3(24, Mz / 128), 256, 0, stream>>>(Xq, Xk, Xv, Wt, b_q, b_k, b_v, Qp, Kp, Vt);

  attn_kernel<<<dim3(Sz / 128, Bz * Hz), 512, 0, stream>>>(Qp, Kp, Vt, Ao);

  gemm_fc<<<dim3(Dz / 64, Mz / 128), 256, 0, stream>>>(Ao, Wtf, b_fc, out);
}

// Round 8
// 246.340 us; speedup vs baseline: 1.0550x; 1.0390x over previous
//
#include <hip/hip_runtime.h>
#include <stdint.h>

#define Bz 2
#define Sz 2048
#define Dz 1024
#define Hz 16
#define HDz 64
#define Mz (Bz*Sz)   // 4096

typedef unsigned short u16;
typedef __attribute__((ext_vector_type(8))) __bf16 bf16x8;
typedef __attribute__((ext_vector_type(4))) __bf16 bf16x4;
typedef __attribute__((ext_vector_type(8))) unsigned short u16x8;
typedef __attribute__((ext_vector_type(4))) unsigned short u16x4;
typedef __attribute__((ext_vector_type(4))) float f32x4;
typedef __attribute__((ext_vector_type(4))) short s16x4;

#define C1 0.1803368801111243f   /* 0.125 * log2(e) */

__device__ __forceinline__ u16 f2bf(float f) {
  union { float f; unsigned u; } v; v.f = f;
  unsigned r = v.u + 0x7fffu + ((v.u >> 16) & 1u);
  return (u16)(r >> 16);
}

__device__ __forceinline__ void async16(void* lds, const void* g) {
  __builtin_amdgcn_global_load_lds(
      (const __attribute__((address_space(1))) unsigned int*)g,
      (__attribute__((address_space(3))) unsigned int*)lds, 16, 0, 0);
}

// ---------- merged preproc: grid (n4/256, 4). role<3 = fp32->bf16 q/k/v; role==3 =
// weight transpose+cvt, weight = blockIdx.x>>10, tile = blockIdx.x&1023 (no idle blocks).
__global__ void __launch_bounds__(256)
prep_kernel(const float* __restrict__ q, const float* __restrict__ k,
            const float* __restrict__ v,
            const float* __restrict__ w0, const float* __restrict__ w1,
            const float* __restrict__ w2, const float* __restrict__ w3,
            u16* __restrict__ xq, u16* __restrict__ xk, u16* __restrict__ xv,
            u16* __restrict__ Wt, int n4) {
  __shared__ __align__(16) float t[32][33];
  const int role = blockIdx.y;
  if (role < 3) {
    const float* in = role == 0 ? q : role == 1 ? k : v;
    u16* out = role == 0 ? xq : role == 1 ? xk : xv;
    int i = blockIdx.x * 256 + threadIdx.x;
    if (i < n4) {
      float4 f = ((const float4*)in)[i];
      ((ushort4*)out)[i] = make_ushort4(f2bf(f.x), f2bf(f.y), f2bf(f.z), f2bf(f.w));
    }
  } else {
    const int z = blockIdx.x >> 10;            // weight index 0..3
    const int tile = blockIdx.x & 1023;        // 32x32 tile grid
    const float* W = z == 0 ? w0 : z == 1 ? w1 : z == 2 ? w2 : w3;
    u16* o = Wt + (size_t)z * Dz * Dz;
    const int n0 = (tile & 31) * 32, k0 = (tile >> 5) * 32;
    const int x = threadIdx.x & 31, y = threadIdx.x >> 5;   // (32,8)
#pragma unroll
    for (int i = 0; i < 4; ++i)
      t[y + i*8][x] = W[(size_t)(k0 + y + i*8) * Dz + n0 + x];
    __syncthreads();
#pragma unroll
    for (int i = 0; i < 4; ++i)
      o[(size_t)(n0 + y + i*8) * Dz + k0 + x] = f2bf(t[x][y + i*8]);
  }
}

// -------- fused QKV GEMM: 128x128 tile (R2-proven structure) --------
// XCD-aware work remap: all 32 m-blocks of one (sel,n0) land on one XCD (f%8) so the
// shared B-panel stays in that XCD's L2. Q output pre-scaled by C1.
__global__ void __launch_bounds__(256)
gemm_qkv(const u16* __restrict__ xq, const u16* __restrict__ xk, const u16* __restrict__ xv,
         const u16* __restrict__ Wt3,
         const float* __restrict__ bq, const float* __restrict__ bk, const float* __restrict__ bv,
         u16* __restrict__ Qp, u16* __restrict__ Kp, u16* __restrict__ Vp)
{
  __shared__ __align__(16) u16 lA[128][32];
  __shared__ __align__(16) u16 lB[128][32];
  const int f = blockIdx.x + 24 * blockIdx.y;      // 0..767
  const int xcd = f & 7, tt = f >> 3;              // tt 0..95
  const int nsel = xcd * 3 + (tt % 3);             // 0..23, fixed XCD per nsel
  const int m0 = (tt / 3) * 128;                   // 0..31 -> m tile
  const int sel = nsel >> 3;
  const int n0 = (nsel & 7) * 128;
  const u16* A = sel == 0 ? xq : sel == 1 ? xk : xv;
  const u16* Bt = Wt3 + (size_t)sel * Dz * Dz;
  const float* bias = sel == 0 ? bq : sel == 1 ? bk : bv;
  u16* Cv = sel == 0 ? Qp : sel == 1 ? Kp : Vp;
  const float cs = sel == 0 ? C1 : 1.0f;

  const int tid = threadIdx.x;
  const int w = tid >> 6, lane = tid & 63;
  const int wm = (w >> 1) * 64, wn = (w & 1) * 64;
  const int l16 = lane & 15, qd = lane >> 4;

  f32x4 acc[4][4];
#pragma unroll
  for (int i = 0; i < 4; ++i)
#pragma unroll
    for (int j = 0; j < 4; ++j) acc[i][j] = (f32x4){0.f, 0.f, 0.f, 0.f};

  const int r0 = tid >> 2, c0 = (tid & 3) * 8;
  const int r1 = r0 + 64;

  for (int k0 = 0; k0 < Dz; k0 += 32) {
    __syncthreads();
    async16(&lA[r0][c0], A  + (size_t)(m0 + r0) * Dz + k0 + c0);
    async16(&lB[r0][c0], Bt + (size_t)(n0 + r0) * Dz + k0 + c0);
    async16(&lA[r1][c0], A  + (size_t)(m0 + r1) * Dz + k0 + c0);
    async16(&lB[r1][c0], Bt + (size_t)(n0 + r1) * Dz + k0 + c0);
    __syncthreads();
    bf16x8 af[4], bfv[4];
#pragma unroll
    for (int t = 0; t < 4; ++t) {
      af[t]  = *(const bf16x8*)&lA[wm + t * 16 + l16][qd * 8];
      bfv[t] = *(const bf16x8*)&lB[wn + t * 16 + l16][qd * 8];
    }
#pragma unroll
    for (int mt = 0; mt < 4; ++mt)
#pragma unroll
      for (int nt = 0; nt < 4; ++nt)
        acc[mt][nt] = __builtin_amdgcn_mfma_f32_16x16x32_bf16(af[mt], bfv[nt], acc[mt][nt], 0, 0, 0);
  }

#pragma unroll
  for (int nt = 0; nt < 4; ++nt) {
    const int n = n0 + wn + nt * 16 + l16;
    const float bvl = bias[n];
#pragma unroll
    for (int mt = 0; mt < 4; ++mt)
#pragma unroll
      for (int r = 0; r < 4; ++r) {
        const int m = m0 + wm + mt * 16 + qd * 4 + r;
        Cv[(size_t)m * Dz + n] = f2bf((acc[mt][nt][r] + bvl) * cs);
      }
  }
}

// ---- Vp[B*S][D] bf16 -> Vt[B][H][HD][S] bf16 (per-head transpose; R2-proven) ----
__global__ void __launch_bounds__(256)
vtrans_kernel(const u16* __restrict__ Vp, u16* __restrict__ Vt) {
  __shared__ __align__(16) u16 t[64][72];
  int s0 = blockIdx.x * 64, bh = blockIdx.y;
  int b = bh >> 4;
  int h = bh & 15;
  int tid = threadIdx.x;
#pragma unroll
  for (int p = 0; p < 4; ++p) {
    int c = p * 256 + tid;
    int row = c >> 4, off = (c & 15) * 4;
    ushort4 v = *(const ushort4*)(Vp + (size_t)(b * Sz + s0 + row) * Dz + h * 64 + off);
    *(ushort4*)&t[row][off] = v;
  }
  __syncthreads();
#pragma unroll
  for (int p = 0; p < 4; ++p) {
    int c = p * 256 + tid;
    int d = c >> 4, sc = (c & 15) * 4;
    ushort4 v = make_ushort4(t[sc + 0][d], t[sc + 1][d], t[sc + 2][d], t[sc + 3][d]);
    *(ushort4*)(Vt + (size_t)(bh * 64 + d) * Sz + s0 + sc) = v;
  }
}

// -------- FC GEMM: 128(M)x64(N) tile, XCD-aware remap (B-panel per XCD) --------
__global__ void __launch_bounds__(256)
gemm_fc(const u16* __restrict__ A, const u16* __restrict__ Bt,
        const float* __restrict__ bias, float* __restrict__ C)
{
  __shared__ __align__(16) u16 lA[128][32];
  __shared__ __align__(16) u16 lB[64][32];
  const int f = blockIdx.x + 16 * blockIdx.y;      // 0..511
  const int xcd = f & 7, tt = f >> 3;              // tt 0..63
  const int ntile = xcd * 2 + (tt & 1);            // 0..15
  const int m0 = (tt >> 1) * 128;                  // 0..31
  const int n0 = ntile * 64;
  const int tid = threadIdx.x;
  const int w = tid >> 6, lane = tid & 63;
  const int wm = (w >> 1) * 64, wn = (w & 1) * 32;
  const int l16 = lane & 15, qd = lane >> 4;

  f32x4 acc[4][2];
#pragma unroll
  for (int i = 0; i < 4; ++i)
#pragma unroll
    for (int j = 0; j < 2; ++j) acc[i][j] = (f32x4){0.f, 0.f, 0.f, 0.f};

  const int r0 = tid >> 2, c0 = (tid & 3) * 8;

  for (int k0 = 0; k0 < Dz; k0 += 32) {
    __syncthreads();
    async16(&lA[r0][c0],      A  + (size_t)(m0 + r0) * Dz + k0 + c0);
    async16(&lA[r0 + 64][c0], A  + (size_t)(m0 + r0 + 64) * Dz + k0 + c0);
    async16(&lB[r0][c0],      Bt + (size_t)(n0 + r0) * Dz + k0 + c0);
    __syncthreads();
    bf16x8 af[4], bfv[2];
#pragma unroll
    for (int t = 0; t < 4; ++t)
      af[t] = *(const bf16x8*)&lA[wm + t * 16 + l16][qd * 8];
#pragma unroll
    for (int t = 0; t < 2; ++t)
      bfv[t] = *(const bf16x8*)&lB[wn + t * 16 + l16][qd * 8];
#pragma unroll
    for (int mt = 0; mt < 4; ++mt)
#pragma unroll
      for (int nt = 0; nt < 2; ++nt)
        acc[mt][nt] = __builtin_amdgcn_mfma_f32_16x16x32_bf16(af[mt], bfv[nt], acc[mt][nt], 0, 0, 0);
  }

#pragma unroll
  for (int nt = 0; nt < 2; ++nt) {
    const int n = n0 + wn + nt * 16 + l16;
    const float bvl = bias[n];
#pragma unroll
    for (int mt = 0; mt < 4; ++mt)
#pragma unroll
      for (int r = 0; r < 4; ++r) {
        const int m = m0 + wm + mt * 16 + qd * 4 + r;
        C[(size_t)m * Dz + n] = acc[mt][nt][r] + bvl;
      }
  }
}

// ---------------- fused flash-style attention (shift-0 softmax) ----------------
// R7 structure (72.3 us) + two fixes:
// (1) V staging back to ONE b128 store (conflict-free 8-lane phases); the XOR-swizzle
//     involution (addr col ^= 4 u16 when row bit3 set) is applied by ROTATING the data
//     halves (vs[i] = v[i^4]) instead of splitting into two conflicted b64 stores.
// (2) XCD-aware work remap: all 16 q-blocks of one head land on one XCD (f&7) so the
//     shared K/V (512 KB/head) stays in that XCD's L2 (FETCH was 69.7 MB vs ~25 unique).
__global__ void __launch_bounds__(512, 4)
attn_kernel(const u16* __restrict__ Qp, const u16* __restrict__ Kp,
            const u16* __restrict__ Vt, u16* __restrict__ Ao)
{
  __shared__ __align__(16) u16 lK[128][72];     // stride 144 B (≡16 mod 128)
  __shared__ __align__(16) u16 lV[64][136];     // stride 272 B, XOR-swizzled cols

  const int f = blockIdx.x + 16 * blockIdx.y;   // 0..511
  const int xcd = f & 7, j = f >> 3;            // j 0..63
  const int bh = xcd * 4 + (j >> 4);            // 0..31: fixed XCD per head
  const int q0 = (j & 15) * 128;
  const int b = bh >> 4, h = bh & 15;
  const int tid = threadIdx.x, w = tid >> 6, lane = tid & 63;
  const int l16 = lane & 15, qd = lane >> 4;

  const int krow = tid >> 3, kcol = (tid & 7) * 8;    // + p*64 rows (krow 0..63)
  const int vrow = tid >> 4, vcol = (tid & 15) * 8;   // + p*32 rows (vrow 0..31)
  const bool vswW = (vrow >> 3) & 1;                  // write-side involution select
  const int vswR = ((l16 >> 3) & 1) << 2;             // read-side swizzle (lane-const)

  // prefetch tile 0 into registers
  u16x8 kreg[2], vreg[2];
#pragma unroll
  for (int p = 0; p < 2; ++p) {
    kreg[p] = *(const u16x8*)(Kp + (size_t)(b * Sz + p * 64 + krow) * Dz + h * 64 + kcol);
    vreg[p] = *(const u16x8*)(Vt + (size_t)(bh * 64 + p * 32 + vrow) * Sz + vcol);
  }

  // Q fragments in registers (pre-scaled by C1), reused for all kv tiles
  bf16x8 qf[2];
#pragma unroll
  for (int ks = 0; ks < 2; ++ks)
    qf[ks] = *(const bf16x8*)(Qp + (size_t)(b * Sz + q0 + w * 16 + l16) * Dz
                              + h * 64 + ks * 32 + qd * 8);

  f32x4 oacc[4];
#pragma unroll
  for (int j2 = 0; j2 < 4; ++j2) oacc[j2] = (f32x4){0.f, 0.f, 0.f, 0.f};
  float lsum = 0.f;

  for (int t = 0; t < Sz / 128; ++t) {
    __syncthreads();
#pragma unroll
    for (int p = 0; p < 2; ++p) {
      *(u16x8*)&lK[p * 64 + krow][kcol] = kreg[p];
      const u16x8 v = vreg[p];
      u16x8 vs;
#pragma unroll
      for (int i = 0; i < 8; ++i) vs[i] = vswW ? v[i ^ 4] : v[i];
      *(u16x8*)&lV[p * 32 + vrow][vcol] = vs;
    }
    if (t + 1 < Sz / 128) {
      const int kv = (t + 1) * 128;
#pragma unroll
      for (int p = 0; p < 2; ++p) {
        kreg[p] = *(const u16x8*)(Kp + (size_t)(b * Sz + kv + p * 64 + krow) * Dz + h * 64 + kcol);
        vreg[p] = *(const u16x8*)(Vt + (size_t)(bh * 64 + p * 32 + vrow) * Sz + kv + vcol);
      }
    }
    __syncthreads();

    // per 16-s strip: S^T = K @ Q^T ; P = exp2 in-register ; O += P @ V ; lsum += sum(P)
#pragma unroll
    for (int nt = 0; nt < 8; ++nt) {
      const bf16x8 kf0 = *(const bf16x8*)&lK[nt * 16 + l16][qd * 8];
      const bf16x8 kf1 = *(const bf16x8*)&lK[nt * 16 + l16][32 + qd * 8];
      f32x4 st = (f32x4){0.f, 0.f, 0.f, 0.f};
      st = __builtin_amdgcn_mfma_f32_16x16x32_bf16(kf0, qf[0], st, 0, 0, 0);
      st = __builtin_amdgcn_mfma_f32_16x16x32_bf16(kf1, qf[1], st, 0, 0, 0);
      const float e0 = exp2f(st[0]), e1 = exp2f(st[1]);
      const float e2 = exp2f(st[2]), e3 = exp2f(st[3]);
      lsum += (e0 + e1) + (e2 + e3);
      bf16x4 pb;
      pb[0] = (__bf16)e0; pb[1] = (__bf16)e1; pb[2] = (__bf16)e2; pb[3] = (__bf16)e3;
      const s16x4 pf = __builtin_bit_cast(s16x4, pb);
#pragma unroll
      for (int nd = 0; nd < 4; ++nd) {
        const s16x4 vf = *(const s16x4*)&lV[nd * 16 + l16][(nt * 16 + qd * 4) ^ vswR];
        oacc[nd] = __builtin_amdgcn_mfma_f32_16x16x16bf16_1k(pf, vf, oacc[nd], 0, 0, 0);
      }
    }
  }

  // rowsum finalize + normalize + store
  lsum += __shfl_xor(lsum, 16, 64);
  lsum += __shfl_xor(lsum, 32, 64);
#pragma unroll
  for (int r = 0; r < 4; ++r) {
    const float inv = 1.0f / __shfl(lsum, qd * 4 + r, 64);
    const int row = q0 + w * 16 + qd * 4 + r;
#pragma unroll
    for (int nd = 0; nd < 4; ++nd) {
      const int col = h * 64 + nd * 16 + l16;
      Ao[(size_t)(b * Sz + row) * Dz + col] = f2bf(oacc[nd][r] * inv);
    }
  }
}

// ---------------- host launch ----------------
extern "C" void kernel_launch(void* const* d_in, const int* in_sizes, int n_in,
                              void* d_out, int out_size, void* d_ws, size_t ws_size,
                              hipStream_t stream) {
  const float* query = (const float*)d_in[0];
  const float* key   = (const float*)d_in[1];
  const float* value = (const float*)d_in[2];
  const float* w_q  = (const float*)d_in[3];
  const float* b_q  = (const float*)d_in[4];
  const float* w_k  = (const float*)d_in[5];
  const float* b_k  = (const float*)d_in[6];
  const float* w_v  = (const float*)d_in[7];
  const float* b_v  = (const float*)d_in[8];
  const float* w_fc = (const float*)d_in[9];
  const float* b_fc = (const float*)d_in[10];
  float* out = (float*)d_out;

  const size_t XE = (size_t)Mz * Dz;   // 4 Mi elements
  const size_t WE = (size_t)Dz * Dz;   // 1 Mi elements
  u16* Xq  = (u16*)d_ws;               // bf16 inputs
  u16* Xk  = Xq + XE;
  u16* Xv  = Xk + XE;
  u16* Wt  = Xv + XE;                  // 4 stacked transposed weights [N][K]: q,k,v,fc
  u16* Wtf = Wt + 3 * WE;
  u16* Qp  = Wt + 4 * WE;              // projections
  u16* Kp  = Qp + XE;
  u16* Vp  = Kp + XE;
  u16* Vt  = Xk;                       // reuse: Xk dead after QKV projections
  u16* Ao  = Xq;                       // reuse: Xq dead after QKV projections

  const int n4 = (int)(XE / 4);
  prep_kernel<<<dim3(n4 / 256, 4), 256, 0, stream>>>(query, key, value,
                                                     w_q, w_k, w_v, w_fc,
                                                     Xq, Xk, Xv, Wt, n4);

  gemm_qkv<<<dim3(24, Mz / 128), 256, 0, stream>>>(Xq, Xk, Xv, Wt, b_q, b_k, b_v, Qp, Kp, Vp);

  vtrans_kernel<<<dim3(Sz / 64, Bz * Hz), 256, 0, stream>>>(Vp, Vt);

  attn_kernel<<<dim3(Sz / 128, Bz * Hz), 512, 0, stream>>>(Qp, Kp, Vt, Ao);

  gemm_fc<<<dim3(Dz / 64, Mz / 128), 256, 0, stream>>>(Ao, Wtf, b_fc, out);
}

// Round 9
// 246.324 us; speedup vs baseline: 1.0551x; 1.0001x over previous
//
#include <hip/hip_runtime.h>
#include <stdint.h>

#define Bz 2
#define Sz 2048
#define Dz 1024
#define Hz 16
#define HDz 64
#define Mz (Bz*Sz)   // 4096

typedef unsigned short u16;
typedef __attribute__((ext_vector_type(8))) __bf16 bf16x8;
typedef __attribute__((ext_vector_type(4))) __bf16 bf16x4;
typedef __attribute__((ext_vector_type(8))) unsigned short u16x8;
typedef __attribute__((ext_vector_type(4))) unsigned short u16x4;
typedef __attribute__((ext_vector_type(4))) float f32x4;
typedef __attribute__((ext_vector_type(4))) short s16x4;

#define C1 0.1803368801111243f   /* 0.125 * log2(e) */

__device__ __forceinline__ u16 f2bf(float f) {
  union { float f; unsigned u; } v; v.f = f;
  unsigned r = v.u + 0x7fffu + ((v.u >> 16) & 1u);
  return (u16)(r >> 16);
}

__device__ __forceinline__ void async16(void* lds, const void* g) {
  __builtin_amdgcn_global_load_lds(
      (const __attribute__((address_space(1))) unsigned int*)g,
      (__attribute__((address_space(3))) unsigned int*)lds, 16, 0, 0);
}

// ---------- merged preproc: grid (n4/256, 4). role<3 = fp32->bf16 q/k/v; role==3 =
// weight transpose+cvt, weight = blockIdx.x>>10, tile = blockIdx.x&1023 (no idle blocks).
__global__ void __launch_bounds__(256)
prep_kernel(const float* __restrict__ q, const float* __restrict__ k,
            const float* __restrict__ v,
            const float* __restrict__ w0, const float* __restrict__ w1,
            const float* __restrict__ w2, const float* __restrict__ w3,
            u16* __restrict__ xq, u16* __restrict__ xk, u16* __restrict__ xv,
            u16* __restrict__ Wt, int n4) {
  __shared__ __align__(16) float t[32][33];
  const int role = blockIdx.y;
  if (role < 3) {
    const float* in = role == 0 ? q : role == 1 ? k : v;
    u16* out = role == 0 ? xq : role == 1 ? xk : xv;
    int i = blockIdx.x * 256 + threadIdx.x;
    if (i < n4) {
      float4 f = ((const float4*)in)[i];
      ((ushort4*)out)[i] = make_ushort4(f2bf(f.x), f2bf(f.y), f2bf(f.z), f2bf(f.w));
    }
  } else {
    const int z = blockIdx.x >> 10;            // weight index 0..3
    const int tile = blockIdx.x & 1023;        // 32x32 tile grid
    const float* W = z == 0 ? w0 : z == 1 ? w1 : z == 2 ? w2 : w3;
    u16* o = Wt + (size_t)z * Dz * Dz;
    const int n0 = (tile & 31) * 32, k0 = (tile >> 5) * 32;
    const int x = threadIdx.x & 31, y = threadIdx.x >> 5;   // (32,8)
#pragma unroll
    for (int i = 0; i < 4; ++i)
      t[y + i*8][x] = W[(size_t)(k0 + y + i*8) * Dz + n0 + x];
    __syncthreads();
#pragma unroll
    for (int i = 0; i < 4; ++i)
      o[(size_t)(n0 + y + i*8) * Dz + k0 + x] = f2bf(t[x][y + i*8]);
  }
}

// -------- fused QKV GEMM: 128x128 tile + conflict-free LDS swizzle --------
// [128][32] u16 tiles have row-stride 64 B: rows r,r+2 alias banks -> 4-way conflict on
// every fragment ds_read_b128 (x1.58, m136). Fix (rule 21): keep global_load_lds linear
// dest, pre-swizzle the GLOBAL source 16B-chunk (chunk' = chunk ^ ((row>>1)&3)), and
// read fragments at col (qd ^ ((l16>>1)&3))*8 — lane-constant XOR, bank-quad-disjoint.
// XCD-aware work remap keeps each B-panel on one XCD's L2. Q pre-scaled by C1.
__global__ void __launch_bounds__(256)
gemm_qkv(const u16* __restrict__ xq, const u16* __restrict__ xk, const u16* __restrict__ xv,
         const u16* __restrict__ Wt3,
         const float* __restrict__ bq, const float* __restrict__ bk, const float* __restrict__ bv,
         u16* __restrict__ Qp, u16* __restrict__ Kp, u16* __restrict__ Vp)
{
  __shared__ __align__(16) u16 lA[128][32];
  __shared__ __align__(16) u16 lB[128][32];
  const int f = blockIdx.x + 24 * blockIdx.y;      // 0..767
  const int xcd = f & 7, tt = f >> 3;              // tt 0..95
  const int nsel = xcd * 3 + (tt % 3);             // 0..23, fixed XCD per nsel
  const int m0 = (tt / 3) * 128;                   // 0..31 -> m tile
  const int sel = nsel >> 3;
  const int n0 = (nsel & 7) * 128;
  const u16* A = sel == 0 ? xq : sel == 1 ? xk : xv;
  const u16* Bt = Wt3 + (size_t)sel * Dz * Dz;
  const float* bias = sel == 0 ? bq : sel == 1 ? bk : bv;
  u16* Cv = sel == 0 ? Qp : sel == 1 ? Kp : Vp;
  const float cs = sel == 0 ? C1 : 1.0f;

  const int tid = threadIdx.x;
  const int w = tid >> 6, lane = tid & 63;
  const int wm = (w >> 1) * 64, wn = (w & 1) * 64;
  const int l16 = lane & 15, qd = lane >> 4;
  const int swr = (l16 >> 1) & 3;                  // read-side swizzle (lane-const)

  f32x4 acc[4][4];
#pragma unroll
  for (int i = 0; i < 4; ++i)
#pragma unroll
    for (int j = 0; j < 4; ++j) acc[i][j] = (f32x4){0.f, 0.f, 0.f, 0.f};

  const int r0 = tid >> 2, r1 = r0 + 64;
  // source-side swizzled col (u16 units): chunk tid&3 XOR (row>>1)&3 ; same for r1 (64/2%4==0)
  const int c0s = (((tid & 3) ^ ((r0 >> 1) & 3)) * 8);
  const int c0 = (tid & 3) * 8;                    // linear dest col

  for (int k0 = 0; k0 < Dz; k0 += 32) {
    __syncthreads();
    async16(&lA[r0][c0], A  + (size_t)(m0 + r0) * Dz + k0 + c0s);
    async16(&lB[r0][c0], Bt + (size_t)(n0 + r0) * Dz + k0 + c0s);
    async16(&lA[r1][c0], A  + (size_t)(m0 + r1) * Dz + k0 + c0s);
    async16(&lB[r1][c0], Bt + (size_t)(n0 + r1) * Dz + k0 + c0s);
    __syncthreads();
    bf16x8 af[4], bfv[4];
#pragma unroll
    for (int t = 0; t < 4; ++t) {
      af[t]  = *(const bf16x8*)&lA[wm + t * 16 + l16][(qd ^ swr) * 8];
      bfv[t] = *(const bf16x8*)&lB[wn + t * 16 + l16][(qd ^ swr) * 8];
    }
#pragma unroll
    for (int mt = 0; mt < 4; ++mt)
#pragma unroll
      for (int nt = 0; nt < 4; ++nt)
        acc[mt][nt] = __builtin_amdgcn_mfma_f32_16x16x32_bf16(af[mt], bfv[nt], acc[mt][nt], 0, 0, 0);
  }

#pragma unroll
  for (int nt = 0; nt < 4; ++nt) {
    const int n = n0 + wn + nt * 16 + l16;
    const float bvl = bias[n];
#pragma unroll
    for (int mt = 0; mt < 4; ++mt)
#pragma unroll
      for (int r = 0; r < 4; ++r) {
        const int m = m0 + wm + mt * 16 + qd * 4 + r;
        Cv[(size_t)m * Dz + n] = f2bf((acc[mt][nt][r] + bvl) * cs);
      }
  }
}

// ---- Vp[B*S][D] bf16 -> Vt[B][H][HD][S] bf16 (per-head transpose; R2-proven) ----
__global__ void __launch_bounds__(256)
vtrans_kernel(const u16* __restrict__ Vp, u16* __restrict__ Vt) {
  __shared__ __align__(16) u16 t[64][72];
  int s0 = blockIdx.x * 64, bh = blockIdx.y;
  int b = bh >> 4;
  int h = bh & 15;
  int tid = threadIdx.x;
#pragma unroll
  for (int p = 0; p < 4; ++p) {
    int c = p * 256 + tid;
    int row = c >> 4, off = (c & 15) * 4;
    ushort4 v = *(const ushort4*)(Vp + (size_t)(b * Sz + s0 + row) * Dz + h * 64 + off);
    *(ushort4*)&t[row][off] = v;
  }
  __syncthreads();
#pragma unroll
  for (int p = 0; p < 4; ++p) {
    int c = p * 256 + tid;
    int d = c >> 4, sc = (c & 15) * 4;
    ushort4 v = make_ushort4(t[sc + 0][d], t[sc + 1][d], t[sc + 2][d], t[sc + 3][d]);
    *(ushort4*)(Vt + (size_t)(bh * 64 + d) * Sz + s0 + sc) = v;
  }
}

// -------- FC GEMM: 128(M)x64(N) tile + conflict-free LDS swizzle + XCD remap --------
__global__ void __launch_bounds__(256)
gemm_fc(const u16* __restrict__ A, const u16* __restrict__ Bt,
        const float* __restrict__ bias, float* __restrict__ C)
{
  __shared__ __align__(16) u16 lA[128][32];
  __shared__ __align__(16) u16 lB[64][32];
  const int f = blockIdx.x + 16 * blockIdx.y;      // 0..511
  const int xcd = f & 7, tt = f >> 3;              // tt 0..63
  const int ntile = xcd * 2 + (tt & 1);            // 0..15
  const int m0 = (tt >> 1) * 128;                  // 0..31
  const int n0 = ntile * 64;
  const int tid = threadIdx.x;
  const int w = tid >> 6, lane = tid & 63;
  const int wm = (w >> 1) * 64, wn = (w & 1) * 32;
  const int l16 = lane & 15, qd = lane >> 4;
  const int swr = (l16 >> 1) & 3;                  // read-side swizzle (lane-const)

  f32x4 acc[4][2];
#pragma unroll
  for (int i = 0; i < 4; ++i)
#pragma unroll
    for (int j = 0; j < 2; ++j) acc[i][j] = (f32x4){0.f, 0.f, 0.f, 0.f};

  const int r0 = tid >> 2;
  const int c0s = (((tid & 3) ^ ((r0 >> 1) & 3)) * 8);
  const int c0 = (tid & 3) * 8;

  for (int k0 = 0; k0 < Dz; k0 += 32) {
    __syncthreads();
    async16(&lA[r0][c0],      A  + (size_t)(m0 + r0) * Dz + k0 + c0s);
    async16(&lA[r0 + 64][c0], A  + (size_t)(m0 + r0 + 64) * Dz + k0 + c0s);
    async16(&lB[r0][c0],      Bt + (size_t)(n0 + r0) * Dz + k0 + c0s);
    __syncthreads();
    bf16x8 af[4], bfv[2];
#pragma unroll
    for (int t = 0; t < 4; ++t)
      af[t] = *(const bf16x8*)&lA[wm + t * 16 + l16][(qd ^ swr) * 8];
#pragma unroll
    for (int t = 0; t < 2; ++t)
      bfv[t] = *(const bf16x8*)&lB[wn + t * 16 + l16][(qd ^ swr) * 8];
#pragma unroll
    for (int mt = 0; mt < 4; ++mt)
#pragma unroll
      for (int nt = 0; nt < 2; ++nt)
        acc[mt][nt] = __builtin_amdgcn_mfma_f32_16x16x32_bf16(af[mt], bfv[nt], acc[mt][nt], 0, 0, 0);
  }

#pragma unroll
  for (int nt = 0; nt < 2; ++nt) {
    const int n = n0 + wn + nt * 16 + l16;
    const float bvl = bias[n];
#pragma unroll
    for (int mt = 0; mt < 4; ++mt)
#pragma unroll
      for (int r = 0; r < 4; ++r) {
        const int m = m0 + wm + mt * 16 + qd * 4 + r;
        C[(size_t)m * Dz + n] = acc[mt][nt][r] + bvl;
      }
  }
}

// ---------------- fused flash-style attention (FROZEN at R8 form) ----------------
__global__ void __launch_bounds__(512, 4)
attn_kernel(const u16* __restrict__ Qp, const u16* __restrict__ Kp,
            const u16* __restrict__ Vt, u16* __restrict__ Ao)
{
  __shared__ __align__(16) u16 lK[128][72];     // stride 144 B (≡16 mod 128)
  __shared__ __align__(16) u16 lV[64][136];     // stride 272 B, XOR-swizzled cols

  const int f = blockIdx.x + 16 * blockIdx.y;   // 0..511
  const int xcd = f & 7, j = f >> 3;            // j 0..63
  const int bh = xcd * 4 + (j >> 4);            // 0..31: fixed XCD per head
  const int q0 = (j & 15) * 128;
  const int b = bh >> 4, h = bh & 15;
  const int tid = threadIdx.x, w = tid >> 6, lane = tid & 63;
  const int l16 = lane & 15, qd = lane >> 4;

  const int krow = tid >> 3, kcol = (tid & 7) * 8;    // + p*64 rows (krow 0..63)
  const int vrow = tid >> 4, vcol = (tid & 15) * 8;   // + p*32 rows (vrow 0..31)
  const bool vswW = (vrow >> 3) & 1;                  // write-side involution select
  const int vswR = ((l16 >> 3) & 1) << 2;             // read-side swizzle (lane-const)

  // prefetch tile 0 into registers
  u16x8 kreg[2], vreg[2];
#pragma unroll
  for (int p = 0; p < 2; ++p) {
    kreg[p] = *(const u16x8*)(Kp + (size_t)(b * Sz + p * 64 + krow) * Dz + h * 64 + kcol);
    vreg[p] = *(const u16x8*)(Vt + (size_t)(bh * 64 + p * 32 + vrow) * Sz + vcol);
  }

  // Q fragments in registers (pre-scaled by C1), reused for all kv tiles
  bf16x8 qf[2];
#pragma unroll
  for (int ks = 0; ks < 2; ++ks)
    qf[ks] = *(const bf16x8*)(Qp + (size_t)(b * Sz + q0 + w * 16 + l16) * Dz
                              + h * 64 + ks * 32 + qd * 8);

  f32x4 oacc[4];
#pragma unroll
  for (int j2 = 0; j2 < 4; ++j2) oacc[j2] = (f32x4){0.f, 0.f, 0.f, 0.f};
  float lsum = 0.f;

  for (int t = 0; t < Sz / 128; ++t) {
    __syncthreads();
#pragma unroll
    for (int p = 0; p < 2; ++p) {
      *(u16x8*)&lK[p * 64 + krow][kcol] = kreg[p];
      const u16x8 v = vreg[p];
      u16x8 vs;
#pragma unroll
      for (int i = 0; i < 8; ++i) vs[i] = vswW ? v[i ^ 4] : v[i];
      *(u16x8*)&lV[p * 32 + vrow][vcol] = vs;
    }
    if (t + 1 < Sz / 128) {
      const int kv = (t + 1) * 128;
#pragma unroll
      for (int p = 0; p < 2; ++p) {
        kreg[p] = *(const u16x8*)(Kp + (size_t)(b * Sz + kv + p * 64 + krow) * Dz + h * 64 + kcol);
        vreg[p] = *(const u16x8*)(Vt + (size_t)(bh * 64 + p * 32 + vrow) * Sz + kv + vcol);
      }
    }
    __syncthreads();

    // per 16-s strip: S^T = K @ Q^T ; P = exp2 in-register ; O += P @ V ; lsum += sum(P)
#pragma unroll
    for (int nt = 0; nt < 8; ++nt) {
      const bf16x8 kf0 = *(const bf16x8*)&lK[nt * 16 + l16][qd * 8];
      const bf16x8 kf1 = *(const bf16x8*)&lK[nt * 16 + l16][32 + qd * 8];
      f32x4 st = (f32x4){0.f, 0.f, 0.f, 0.f};
      st = __builtin_amdgcn_mfma_f32_16x16x32_bf16(kf0, qf[0], st, 0, 0, 0);
      st = __builtin_amdgcn_mfma_f32_16x16x32_bf16(kf1, qf[1], st, 0, 0, 0);
      const float e0 = exp2f(st[0]), e1 = exp2f(st[1]);
      const float e2 = exp2f(st[2]), e3 = exp2f(st[3]);
      lsum += (e0 + e1) + (e2 + e3);
      bf16x4 pb;
      pb[0] = (__bf16)e0; pb[1] = (__bf16)e1; pb[2] = (__bf16)e2; pb[3] = (__bf16)e3;
      const s16x4 pf = __builtin_bit_cast(s16x4, pb);
#pragma unroll
      for (int nd = 0; nd < 4; ++nd) {
        const s16x4 vf = *(const s16x4*)&lV[nd * 16 + l16][(nt * 16 + qd * 4) ^ vswR];
        oacc[nd] = __builtin_amdgcn_mfma_f32_16x16x16bf16_1k(pf, vf, oacc[nd], 0, 0, 0);
      }
    }
  }

  // rowsum finalize + normalize + store
  lsum += __shfl_xor(lsum, 16, 64);
  lsum += __shfl_xor(lsum, 32, 64);
#pragma unroll
  for (int r = 0; r < 4; ++r) {
    const float inv = 1.0f / __shfl(lsum, qd * 4 + r, 64);
    const int row = q0 + w * 16 + qd * 4 + r;
#pragma unroll
    for (int nd = 0; nd < 4; ++nd) {
      const int col = h * 64 + nd * 16 + l16;
      Ao[(size_t)(b * Sz + row) * Dz + col] = f2bf(oacc[nd][r] * inv);
    }
  }
}

// ---------------- host launch ----------------
extern "C" void kernel_launch(void* const* d_in, const int* in_sizes, int n_in,
                              void* d_out, int out_size, void* d_ws, size_t ws_size,
                              hipStream_t stream) {
  const float* query = (const float*)d_in[0];
  const float* key   = (const float*)d_in[1];
  const float* value = (const float*)d_in[2];
  const float* w_q  = (const float*)d_in[3];
  const float* b_q  = (const float*)d_in[4];
  const float* w_k  = (const float*)d_in[5];
  const float* b_k  = (const float*)d_in[6];
  const float* w_v  = (const float*)d_in[7];
  const float* b_v  = (const float*)d_in[8];
  const float* w_fc = (const float*)d_in[9];
  const float* b_fc = (const float*)d_in[10];
  float* out = (float*)d_out;

  const size_t XE = (size_t)Mz * Dz;   // 4 Mi elements
  const size_t WE = (size_t)Dz * Dz;   // 1 Mi elements
  u16* Xq  = (u16*)d_ws;               // bf16 inputs
  u16* Xk  = Xq + XE;
  u16* Xv  = Xk + XE;
  u16* Wt  = Xv + XE;                  // 4 stacked transposed weights [N][K]: q,k,v,fc
  u16* Wtf = Wt + 3 * WE;
  u16* Qp  = Wt + 4 * WE;              // projections
  u16* Kp  = Qp + XE;
  u16* Vp  = Kp + XE;
  u16* Vt  = Xk;                       // reuse: Xk dead after QKV projections
  u16* Ao  = Xq;                       // reuse: Xq dead after QKV projections

  const int n4 = (int)(XE / 4);
  prep_kernel<<<dim3(n4 / 256, 4), 256, 0, stream>>>(query, key, value,
                                                     w_q, w_k, w_v, w_fc,
                                                     Xq, Xk, Xv, Wt, n4);

  gemm_qkv<<<dim3(24, Mz / 128), 256, 0, stream>>>(Xq, Xk, Xv, Wt, b_q, b_k, b_v, Qp, Kp, Vp);

  vtrans_kernel<<<dim3(Sz / 64, Bz * Hz), 256, 0, stream>>>(Vp, Vt);

  attn_kernel<<<dim3(Sz / 128, Bz * Hz), 512, 0, stream>>>(Qp, Kp, Vt, Ao);

  gemm_fc<<<dim3(Dz / 64, Mz / 128), 256, 0, stream>>>(Ao, Wtf, b_fc, out);
}